// Round 1
// 948.073 us; speedup vs baseline: 1.1209x; 1.1209x over previous
//
#include <hip/hip_runtime.h>

// VQ forward on MI355X — round 10: spill-free m97-geometry coarse kernel.
// x: [32768,512] fp32, codebook: [8192,512] fp32.
// d_out (fp32): [16.7M) quantized_st | [1] vq_loss | [32768] idx-as-float
//
// R9 post-mortem: WRITE_SIZE=320MB on coarse == scratch spills. The screen
// phase consumes acc with VALU, so the compiler keeps acc[4][8] (128 regs)
// in arch VGPRs; + fragments + addressing > 256 unified budget -> ~100 regs
// spilled per ci iteration. Fix: per-wave tile 64x128 -> 64x64 (acc[4][4] =
// 64 regs, the proven m97 geometry: block 128x128, 4 waves, BK=32,
// global_load_lds w=16). Live set ~150 regs -> no spill, ~3 blocks/CU.
// ci count doubles (32 tiles of 128 codes) -> more A re-reads, but HBM was
// at 17% and all data L3-fits. XCD swizzle pins each 4MB cb half to the L2
// of the 4 XCDs that use it. Screen min-pass switched u64->u32 (threshold
// needs min dist only; exact tie-break lives in rescore). Distances are
// bit-identical to R9 (same MFMA K-sequence per (row,code)), so candidate
// sets, rescore, and outputs are unchanged (absmax 0 since R1).

#define NROWS 32768
#define KCODES 8192
#define DD 512
#define CAP 24
#define MARGIN 2.5e-4f

typedef __bf16 bf16_t;
typedef __bf16 bf16x4 __attribute__((ext_vector_type(4)));
typedef __bf16 bf16x8 __attribute__((ext_vector_type(8)));
typedef float f32x4 __attribute__((ext_vector_type(4)));

// LDS layout: 16B chunk (row, slot s in 0..3) at byte row*64 + (s^((row>>1)&3))*16.
__device__ __forceinline__ int lofs(int row, int s) {
  return row * 32 + (((s ^ ((row >> 1) & 3))) << 3);   // bf16-element offset
}

__device__ __forceinline__ void gld16(const bf16_t* g, bf16_t* l) {
  __builtin_amdgcn_global_load_lds(
      (const __attribute__((address_space(1))) void*)g,
      (__attribute__((address_space(3))) void*)l, 16, 0, 0);
}

// ---------------- fused: sum of fp32 squares per row (fp64 accumulate, fp32
// round — summation order identical to R9's sumsq_kernel) + bf16 convert.
__global__ __launch_bounds__(256) void prep_kernel(const float* __restrict__ in,
                                                   float* __restrict__ out_sq,
                                                   bf16_t* __restrict__ outb,
                                                   int nrows) {
  const int wave = threadIdx.x >> 6;
  const int lane = threadIdx.x & 63;
  const int row = blockIdx.x * 4 + wave;
  if (row >= nrows) return;
  const float* p = in + (size_t)row * DD;
  double s = 0.0;
#pragma unroll
  for (int j = 0; j < DD / 64; ++j) {
    float v = p[j * 64 + lane];
    float sq = v * v;
    s += (double)sq;
  }
  for (int off = 32; off > 0; off >>= 1) s += __shfl_down(s, off, 64);
  if (lane == 0) out_sq[row] = (float)s;
  // bf16 convert (RNE, elementwise — identical to R9's cvt_kernel). Row is
  // hot in L1 from the sumsq pass; contiguous 16B store per lane.
  const float4* p4 = (const float4*)p;
  float4 a = p4[lane * 2];
  float4 b = p4[lane * 2 + 1];
  bf16x8 o = {(bf16_t)a.x, (bf16_t)a.y, (bf16_t)a.z, (bf16_t)a.w,
              (bf16_t)b.x, (bf16_t)b.y, (bf16_t)b.z, (bf16_t)b.w};
  *(bf16x8*)(outb + (size_t)row * DD + lane * 8) = o;
}

// ---------------- coarse: bf16 MFMA GEMM (16x16x32) + prefix-min margin screen
// Block tile 128 rows x 128 codes, 4 waves each 64x64 (acc[4][4] = 64 regs).
__global__ __launch_bounds__(256, 2) void coarse_kernel(
    const bf16_t* __restrict__ xbf, const bf16_t* __restrict__ cbbf,
    const float* __restrict__ csq, int* __restrict__ cnt_g,
    int* __restrict__ list_g) {
  __shared__ bf16_t As[128 * 32];               //  8 KB
  __shared__ bf16_t Bs[128 * 32];               //  8 KB
  __shared__ unsigned best[128];                // fp32 bits of min dist (d'>0)
  __shared__ int cnt_l[128];
  __shared__ int list_l[128 * CAP];             // 12 KB

  const int tid = threadIdx.x;
  const int w = tid >> 6;
  const int lane = tid & 63;
  const int q = lane >> 4;           // quad: k-group q*8..q*8+7, C rows q*4+reg
  const int l15 = lane & 15;
  const int rOff = (w & 1) * 64;     // wave rows rOff..rOff+63
  const int cOff = (w >> 1) * 64;    // wave cols cOff..cOff+63

  // XCD-aware decode (heuristic: consecutive blockIdx round-robin XCDs).
  // XCDs 0-3 handle half 0, 4-7 half 1 -> each XCD's L2 holds ONE 4MB
  // bf16 codebook half; row-blocks contiguous per XCD.
  const int bid = blockIdx.x;
  const int xcd = bid & 7;
  const int g = bid >> 3;                    // 0..63
  const int half = xcd >> 2;
  const int rowblk = (xcd & 3) * 64 + g;     // 0..255, bijective
  const int row0 = rowblk * 128;
  const int cbase = half * (KCODES / 2);

  for (int i = tid; i < 128; i += 256) { best[i] = 0xFFFFFFFFu; cnt_l[i] = 0; }

  // ---- DMA staging assignments (lane-fixed; only kb / ci vary per round) ----
  // Each gld16 call: 64 lanes x 16B = 16 rows. lane l -> row rb+(l>>2),
  // LDS pos p=l&3, global slot sg = p ^ ((row>>1)&3). LDS dest offset
  // row*64 + p*16 bytes = base + l*16: contiguous in lane order (HW scatter).
  const int sub = lane >> 2;                 // 0..15 row-within-call
  const int pos = lane & 3;
  const bf16_t *agp[2], *bgp[2];
  bf16_t *alp[2], *blp[2];
#pragma unroll
  for (int a = 0; a < 2; ++a) {
    const int row = w * 32 + a * 16 + sub;   // wave w stages rows w*32..+31
    const int sg = pos ^ ((row >> 1) & 3);
    agp[a] = xbf + (size_t)(row0 + row) * DD + sg * 8;
    alp[a] = As + row * 32 + pos * 8;
    bgp[a] = cbbf + (size_t)(cbase + row) * DD + sg * 8;
    blp[a] = Bs + row * 32 + pos * 8;
  }

  // fragment read offsets
  int afofs[4], bfofs[4];
#pragma unroll
  for (int rt = 0; rt < 4; ++rt) afofs[rt] = lofs(rOff + rt * 16 + l15, q);
#pragma unroll
  for (int ct = 0; ct < 4; ++ct) bfofs[ct] = lofs(cOff + ct * 16 + l15, q);

  __syncthreads();   // best/cnt init visible

#pragma unroll 1
  for (int ci = 0; ci < (KCODES / 2) / 128; ++ci) {   // 32 code tiles
    const int c0 = cbase + ci * 128;
    const size_t coff = (size_t)(ci * 128) * DD;
    f32x4 acc[4][4];
#pragma unroll
    for (int rt = 0; rt < 4; ++rt)
#pragma unroll
      for (int ct = 0; ct < 4; ++ct) {
        f32x4 z = {0.f, 0.f, 0.f, 0.f};
        acc[rt][ct] = z;
      }

#pragma unroll 1
    for (int kc = 0; kc < DD / 32; ++kc) {
      const int kb = kc * 32;
      __syncthreads();               // previous round's readers done
      // async DMA this round's tiles into LDS (no VGPR round-trip)
      gld16(agp[0] + kb, alp[0]);
      gld16(agp[1] + kb, alp[1]);
      gld16(bgp[0] + coff + kb, blp[0]);
      gld16(bgp[1] + coff + kb, blp[1]);
      __syncthreads();               // vmcnt(0) drain -> tiles ready

      // fragments + 16 MFMAs (16x16x32, one K=32 step per round)
      bf16x8 af[4], bfr[4];
#pragma unroll
      for (int rt = 0; rt < 4; ++rt) af[rt] = *(const bf16x8*)&As[afofs[rt]];
#pragma unroll
      for (int ct = 0; ct < 4; ++ct) bfr[ct] = *(const bf16x8*)&Bs[bfofs[ct]];
#pragma unroll
      for (int rt = 0; rt < 4; ++rt)
#pragma unroll
        for (int ct = 0; ct < 4; ++ct)
          acc[rt][ct] = __builtin_amdgcn_mfma_f32_16x16x32_bf16(
              af[rt], bfr[ct], acc[rt][ct], 0, 0, 0);
    }

    // ---- screen this 128-code tile. d' = 1 + csq - 2*dot (>0, bit-orderable)
    float cs1[4];
#pragma unroll
    for (int ct = 0; ct < 4; ++ct)
      cs1[ct] = 1.0f + csq[c0 + cOff + ct * 16 + l15];

    // min pass (C/D layout m89: col=lane&15, row=q*4+reg). Threshold needs
    // min DIST only (exact tie-break is rescore's job) -> u32 float-bits min.
#pragma unroll
    for (int rt = 0; rt < 4; ++rt) {
#pragma unroll
      for (int reg = 0; reg < 4; ++reg) {
        float m = fmaf(-2.0f, acc[rt][0][reg], cs1[0]);
#pragma unroll
        for (int ct = 1; ct < 4; ++ct) {
          float d = fmaf(-2.0f, acc[rt][ct][reg], cs1[ct]);
          m = fminf(m, d);
        }
        unsigned mb = __float_as_uint(m);   // d'>0 -> bit order == value order
#pragma unroll
        for (int msk = 1; msk <= 8; msk <<= 1) {
          unsigned o = __shfl_xor(mb, msk, 64);
          mb = mb < o ? mb : o;
        }
        if (l15 == 0) atomicMin(&best[rOff + rt * 16 + q * 4 + reg], mb);
      }
    }
    __syncthreads();

    // append pass vs prefix-min threshold
#pragma unroll
    for (int rt = 0; rt < 4; ++rt) {
#pragma unroll
      for (int reg = 0; reg < 4; ++reg) {
        const int rloc = rOff + rt * 16 + q * 4 + reg;
        const float thr = __uint_as_float(best[rloc]) + MARGIN;
#pragma unroll
        for (int ct = 0; ct < 4; ++ct) {
          float d = fmaf(-2.0f, acc[rt][ct][reg], cs1[ct]);
          if (d <= thr) {
            int pos2 = atomicAdd(&cnt_l[rloc], 1);
            if (pos2 < CAP)
              list_l[rloc * CAP + pos2] = c0 + cOff + ct * 16 + l15;
          }
        }
      }
    }
    __syncthreads();
  }

  // per-half outputs: cnt/list indexed by (row, half)
  for (int i = tid; i < 128; i += 256) cnt_g[(row0 + i) * 2 + half] = cnt_l[i];
  for (int i = tid; i < 128 * CAP; i += 256) {
    const int r = i / CAP, p = i % CAP;
    list_g[((size_t)(row0 + r) * 2 + half) * CAP + p] = list_l[i];
  }
}

// ---------------- phase 2: exact rescore of candidates (R1's bit-exact chain)
__global__ __launch_bounds__(256) void rescore_kernel(
    const float* __restrict__ x, const float* __restrict__ cb,
    const float* __restrict__ xsq, const float* __restrict__ csq,
    const int* __restrict__ list, const int* __restrict__ cnt,
    int* __restrict__ idxbuf) {
  const int row = blockIdx.x * 4 + (threadIdx.x >> 6);
  const int lane = threadIdx.x & 63;
  const int n0 = cnt[row * 2];
  const int n1 = cnt[row * 2 + 1];
  const float xs = xsq[row];
  const float4* xr4 = (const float4*)(x + (size_t)row * DD);
  unsigned long long bestv = ~0ULL;

  if (n0 >= 1 && n0 <= CAP && n1 >= 0 && n1 <= CAP && (n0 + n1) <= 56) {
    int myidx = -1;
    if (lane < n0) myidx = list[((size_t)row * 2) * CAP + lane];
    else if (lane - n0 < n1) myidx = list[((size_t)row * 2 + 1) * CAP + (lane - n0)];
    if (myidx >= 0) {
      const float4* cr4 = (const float4*)(cb + (size_t)myidx * DD);
      float acc = 0.0f;
      for (int k4 = 0; k4 < DD / 4; ++k4) {     // sequential ascending k: R1 order
        float4 xv = xr4[k4];
        float4 cv = cr4[k4];
        acc = fmaf(xv.x, cv.x, acc);
        acc = fmaf(xv.y, cv.y, acc);
        acc = fmaf(xv.z, cv.z, acc);
        acc = fmaf(xv.w, cv.w, acc);
      }
      float t = xs - 2.0f * acc;
      float d = t + csq[myidx];
      bestv = ((unsigned long long)__float_as_uint(d) << 32) | (unsigned)myidx;
    }
  } else {
    // safety fallback: full exact scan
    for (int idx = lane; idx < KCODES; idx += 64) {
      const float4* cr4 = (const float4*)(cb + (size_t)idx * DD);
      float acc = 0.0f;
      for (int k4 = 0; k4 < DD / 4; ++k4) {
        float4 xv = xr4[k4];
        float4 cv = cr4[k4];
        acc = fmaf(xv.x, cv.x, acc);
        acc = fmaf(xv.y, cv.y, acc);
        acc = fmaf(xv.z, cv.z, acc);
        acc = fmaf(xv.w, cv.w, acc);
      }
      float t = xs - 2.0f * acc;
      float d = t + csq[idx];
      unsigned long long pk =
          ((unsigned long long)__float_as_uint(d) << 32) | (unsigned)idx;
      if (pk < bestv) bestv = pk;
    }
  }
#pragma unroll
  for (int s = 1; s <= 32; s <<= 1) {
    unsigned long long o = __shfl_xor(bestv, s, 64);
    if (o < bestv) bestv = o;
  }
  if (lane == 0) idxbuf[row] = (int)(bestv & 0xffffffffu);
}

// ---------------- gather + straight-through + loss partial + idx-as-float
__global__ __launch_bounds__(128) void epilogue_kernel(
    const float* __restrict__ x, const float* __restrict__ cb,
    const int* __restrict__ idxbuf, float* __restrict__ out_q,
    float* __restrict__ out_idx_f, double* __restrict__ partials) {
  const int row = blockIdx.x;
  const int t = threadIdx.x;
  const int k = idxbuf[row];

  const float4* xr = (const float4*)(x + (size_t)row * DD);
  const float4* qr = (const float4*)(cb + (size_t)k * DD);
  float4* orow = (float4*)(out_q + (size_t)row * DD);

  float4 xv = xr[t];
  float4 qv = qr[t];
  float dx = qv.x - xv.x, dy = qv.y - xv.y, dz = qv.z - xv.z, dw = qv.w - xv.w;
  float4 o;
  o.x = xv.x + dx; o.y = xv.y + dy; o.z = xv.z + dz; o.w = xv.w + dw;
  orow[t] = o;

  float s0 = dx * dx, s1 = dy * dy, s2 = dz * dz, s3 = dw * dw;
  double part = (double)s0 + (double)s1 + (double)s2 + (double)s3;
  for (int off = 32; off > 0; off >>= 1) part += __shfl_down(part, off, 64);
  __shared__ double red[2];
  const int lane = t & 63, wv = t >> 6;
  if (lane == 0) red[wv] = part;
  __syncthreads();
  if (t == 0) {
    partials[row] = red[0] + red[1];
    out_idx_f[row] = (float)k;
  }
}

// ---------------- reduce partials -> vq_loss
__global__ __launch_bounds__(256) void finalize_kernel(
    const double* __restrict__ partials, float* __restrict__ out_loss) {
  __shared__ double red[256];
  double s = 0.0;
  for (int i = threadIdx.x; i < NROWS; i += 256) s += partials[i];
  red[threadIdx.x] = s;
  __syncthreads();
  for (int st = 128; st > 0; st >>= 1) {
    if (threadIdx.x < st) red[threadIdx.x] += red[threadIdx.x + st];
    __syncthreads();
  }
  if (threadIdx.x == 0) {
    double mean = red[0] / ((double)NROWS * (double)DD);
    float cl = (float)mean;
    out_loss[0] = cl + 0.25f * cl;
  }
}

extern "C" void kernel_launch(void* const* d_in, const int* in_sizes, int n_in,
                              void* d_out, int out_size, void* d_ws,
                              size_t ws_size, hipStream_t stream) {
  const float* x = (const float*)d_in[0];
  const float* cb = (const float*)d_in[1];
  float* out = (float*)d_out;

  // ws: partials | idxbuf | csq | xsq | cnt(2/row) | list(2 halves/row)
  char* ws = (char*)d_ws;
  double* partials = (double*)ws;                          // 262144 B
  int* idxbuf = (int*)(ws + 262144);                       // 131072 B
  float* csq = (float*)(ws + 262144 + 131072);             //  32768 B
  float* xsq = (float*)(ws + 262144 + 131072 + 32768);     // 131072 B
  int* cnt = (int*)(ws + 262144 + 131072 + 32768 + 131072);           // 262144 B
  int* list = (int*)(ws + 262144 + 131072 + 32768 + 131072 + 262144); // 6.3 MB

  // bf16 copies live in d_out scratch (overwritten by epilogue later)
  bf16_t* cbbf = (bf16_t*)d_out;
  bf16_t* xbf = cbbf + (size_t)KCODES * DD;

  prep_kernel<<<KCODES / 4, 256, 0, stream>>>(cb, csq, cbbf, KCODES);
  prep_kernel<<<NROWS / 4, 256, 0, stream>>>(x, xsq, xbf, NROWS);
  coarse_kernel<<<512, 256, 0, stream>>>(xbf, cbbf, csq, cnt, list);
  rescore_kernel<<<NROWS / 4, 256, 0, stream>>>(x, cb, xsq, csq, list, cnt, idxbuf);
  epilogue_kernel<<<NROWS, 128, 0, stream>>>(x, cb, idxbuf, out,
                                             out + 16777216 + 1, partials);
  finalize_kernel<<<1, 256, 0, stream>>>(partials, out + 16777216);
}